// Round 12
// baseline (194.822 us; speedup 1.0000x reference)
//
#include <hip/hip_runtime.h>
#include <stdint.h>

// MultiBoxLoss B=16, P=43008, G=128.
// R12: split k_match -> k_iou + k_bp (diagnostic: top-5 was saturated by
//      k_match replicas, hiding ~100us of non-match time). k_fin merged into
//      k_tail (last-of-16-blocks counter; 16 fences only). k_main: reciprocal
//      muls instead of 14 divides, single-expf logsumexp.
//      6 dispatches: memset, k_iou, k_bp, k_scatter, k_main, k_tail.

#define GC 8    // GTs per k_bp block
#define PPI 2   // priors/thread in k_iou

__device__ __forceinline__ float sl1(float x) {
  float a = fabsf(x);
  return a < 1.f ? 0.5f * a * a : a - 0.5f;
}

__device__ __forceinline__ double dwave(double v) {
#pragma unroll
  for (int o = 32; o; o >>= 1) v += __shfl_down(v, o);
  return v;
}

__global__ __launch_bounds__(256) void k_iou(
    const float* __restrict__ priors, const float* __restrict__ targets,
    float* __restrict__ bto, int* __restrict__ bti, int P, int G, int PTI) {
  int tid = threadIdx.x;
  __shared__ float4 sgt[128];
  __shared__ float sga[128];

  int b = blockIdx.x / PTI, tile = blockIdx.x % PTI;
  int base = tile * (256 * PPI);
  for (int g = tid; g < G; g += 256) {
    const float* t = targets + ((size_t)b * G + g) * 15;
    float x1 = t[0], y1 = t[1], x2 = t[2], y2 = t[3];
    sgt[g] = make_float4(x1, y1, x2, y2);
    sga[g] = (x2 - x1) * (y2 - y1);
  }
  __syncthreads();

  float px1[PPI], py1[PPI], px2[PPI], py2[PPI], pa[PPI];
  float bi[PPI], sb[PPI];
  int bidx[PPI];
#pragma unroll
  for (int k = 0; k < PPI; ++k) {
    int p = base + tid + k * 256;
    int pl = p < P ? p : P - 1;
    float4 pr = ((const float4*)priors)[pl];
    px1[k] = pr.x - pr.z * 0.5f; py1[k] = pr.y - pr.w * 0.5f;
    px2[k] = pr.x + pr.z * 0.5f; py2[k] = pr.y + pr.w * 0.5f;
    pa[k] = pr.z * pr.w;
    bi[k] = 0.f; sb[k] = 1.f; bidx[k] = 0;
  }

#define IOU_BODY(T, A, GG)                                                 \
  {                                                                        \
    float iw = fminf(T.z, px2[k]) - fmaxf(T.x, px1[k]);                    \
    float ih = fminf(T.w, py2[k]) - fmaxf(T.y, py1[k]);                    \
    float inter = fmaxf(iw, 0.f) * ih; /* neg never wins vs bi>=0 */       \
    float S = A + pa[k];                                                   \
    if (inter * sb[k] > bi[k] * S) { bi[k] = inter; sb[k] = S; bidx[k] = GG; } \
  }

  for (int g = 0; g < G; g += 4) {
    float4 T0 = sgt[g], T1 = sgt[g + 1], T2 = sgt[g + 2], T3 = sgt[g + 3];
    float A0 = sga[g], A1 = sga[g + 1], A2 = sga[g + 2], A3 = sga[g + 3];
#pragma unroll
    for (int k = 0; k < PPI; ++k) {
      IOU_BODY(T0, A0, g)
      IOU_BODY(T1, A1, g + 1)
      IOU_BODY(T2, A2, g + 2)
      IOU_BODY(T3, A3, g + 3)
    }
  }
#undef IOU_BODY
#pragma unroll
  for (int k = 0; k < PPI; ++k) {
    int p = base + tid + k * 256;
    if (p < P) {
      bto[(size_t)b * P + p] = bi[k] / (sb[k] - bi[k]);  // uni = S_b - inter_b
      bti[(size_t)b * P + p] = bidx[k];
    }
  }
}

__global__ __launch_bounds__(256) void k_bp(
    const float* __restrict__ priors, const float* __restrict__ targets,
    unsigned long long* __restrict__ bp, int P, int G, int NGC, int PC) {
  int tid = threadIdx.x;
  __shared__ float4 sgt[GC];
  __shared__ unsigned long long sred[GC * 256];  // 16 KB

  int bc = blockIdx.x;
  int pc = bc % PC;
  int gcb = (bc / PC) % NGC;
  int b = bc / (PC * NGC);
  int g0 = gcb * GC;

  if (tid < GC) {
    int g = g0 + tid;
    float4 v = make_float4(0.f, 0.f, 0.f, 0.f);
    if (g < G) {
      const float* t = targets + ((size_t)b * G + g) * 15;
      v = make_float4(t[0], t[1], t[2], t[3]);
    }
    sgt[tid] = v;
  }
  __syncthreads();

  float gx1[GC], gy1[GC], gx2[GC], gy2[GC], ga[GC];
#pragma unroll
  for (int j = 0; j < GC; ++j) {
    float4 T = sgt[j];
    gx1[j] = T.x; gy1[j] = T.y; gx2[j] = T.z; gy2[j] = T.w;
    ga[j] = (T.z - T.x) * (T.w - T.y);
  }

  int chunk = (P + PC - 1) / PC;
  int ps = pc * chunk;
  int pe = ps + chunk; if (pe > P) pe = P;
  int count = pe - ps;

  float bi[GC], sb[GC];
  unsigned bpp[GC];
#pragma unroll
  for (int j = 0; j < GC; ++j) { bi[j] = 0.f; sb[j] = 1.f; bpp[j] = (unsigned)(ps + tid); }

#define BP_BODY(X1, Y1, X2, Y2, AR, PP)                                     \
  {                                                                         \
    float iw = fminf(gx2[j], X2) - fmaxf(gx1[j], X1);                       \
    float ih = fminf(gy2[j], Y2) - fmaxf(gy1[j], Y1);                       \
    float inter = fmaxf(iw, 0.f) * ih;                                      \
    float S = ga[j] + AR;                                                   \
    if (inter * sb[j] > bi[j] * S) { bi[j] = inter; sb[j] = S; bpp[j] = (unsigned)PP; } \
  }

  for (int i = tid; i < count; i += 1024) {
    int p0 = ps + i;
    int i1 = i + 256, i2 = i + 512, i3 = i + 768;
    int p1 = (i1 < count) ? ps + i1 : p0;  // clamped dup: strict > => no-op
    int p2 = (i2 < count) ? ps + i2 : p0;
    int p3 = (i3 < count) ? ps + i3 : p0;
    float4 q0 = ((const float4*)priors)[p0];
    float4 q1 = ((const float4*)priors)[p1];
    float4 q2 = ((const float4*)priors)[p2];
    float4 q3 = ((const float4*)priors)[p3];
    float ax1 = q0.x - q0.z * 0.5f, ay1 = q0.y - q0.w * 0.5f;
    float ax2 = q0.x + q0.z * 0.5f, ay2 = q0.y + q0.w * 0.5f;
    float aa = q0.z * q0.w;
    float bx1 = q1.x - q1.z * 0.5f, by1 = q1.y - q1.w * 0.5f;
    float bx2 = q1.x + q1.z * 0.5f, by2 = q1.y + q1.w * 0.5f;
    float ba = q1.z * q1.w;
    float cx1 = q2.x - q2.z * 0.5f, cy1 = q2.y - q2.w * 0.5f;
    float cx2 = q2.x + q2.z * 0.5f, cy2 = q2.y + q2.w * 0.5f;
    float ca = q2.z * q2.w;
    float dx1 = q3.x - q3.z * 0.5f, dy1 = q3.y - q3.w * 0.5f;
    float dx2 = q3.x + q3.z * 0.5f, dy2 = q3.y + q3.w * 0.5f;
    float da = q3.z * q3.w;
#pragma unroll
    for (int j = 0; j < GC; ++j) {
      BP_BODY(ax1, ay1, ax2, ay2, aa, p0)
      BP_BODY(bx1, by1, bx2, by2, ba, p1)
      BP_BODY(cx1, cy1, cx2, cy2, ca, p2)
      BP_BODY(dx1, dy1, dx2, dy2, da, p3)
    }
  }
#undef BP_BODY

  // divide early -> packed u64 (iou bits | ~p), LDS max tree
#pragma unroll
  for (int j = 0; j < GC; ++j) {
    float iou = bi[j] / (sb[j] - bi[j]);
    unsigned long long pk =
        ((unsigned long long)__float_as_uint(iou) << 32) | (unsigned)(~bpp[j]);
    sred[j * 256 + tid] = pk;
  }
  __syncthreads();
  {
    int j = tid >> 5, s = tid & 31;
    unsigned long long m = sred[j * 256 + s];
#pragma unroll
    for (int t = 1; t < 8; ++t) {
      unsigned long long v = sred[j * 256 + s + t * 32];
      if (v > m) m = v;
    }
    __syncthreads();
    sred[j * 256 + s] = m;
  }
  __syncthreads();
  if (tid < GC) {
    unsigned long long m = sred[tid * 256];
    for (int s = 1; s < 32; ++s) {
      unsigned long long v = sred[tid * 256 + s];
      if (v > m) m = v;
    }
    int g = g0 + tid;
    if (g < G) atomicMax(&bp[(size_t)b * G + g], m);
  }
}

__global__ void k_scatter(const unsigned long long* __restrict__ bp,
                          float* __restrict__ bto, int* __restrict__ bti,
                          int* __restrict__ anyv, int P, int G) {
  int b = blockIdx.x, g = threadIdx.x;
  __shared__ unsigned spp[128];
  __shared__ int s_any;
  if (g == 0) s_any = 0;
  __syncthreads();
  unsigned long long m = bp[(size_t)b * G + g];
  unsigned pp = ~(unsigned)m;
  float val = __uint_as_float((unsigned)(m >> 32));
  bool ok = (m != 0ULL);
  float oldv = 0.f;
  if (ok) oldv = bto[(size_t)b * P + pp];
  spp[g] = ok ? pp : 0xFFFFFFFFu;
  if (ok && val >= 0.2f) s_any = 1;
  __syncthreads();
  bool win = ok;
  for (int g2 = g + 1; g2 < G; ++g2)
    if (spp[g2] == pp) win = false;
  if (win) {
    bto[(size_t)b * P + pp] = (val >= 0.2f) ? 2.0f : oldv;
    bti[(size_t)b * P + pp] = g;
  }
  __syncthreads();
  if (g == 0) anyv[b] = s_any;
}

__global__ __launch_bounds__(256) void k_main(
    const float* __restrict__ loc, const float* __restrict__ conf,
    const float* __restrict__ lm, const float* __restrict__ priors,
    const float* __restrict__ targets, const float* __restrict__ bto,
    const int* __restrict__ bti, const int* __restrict__ anyv,
    float* __restrict__ mine, unsigned* __restrict__ h1,
    double* __restrict__ pll, double* __restrict__ pllm,
    double* __restrict__ plc, double* __restrict__ msum,
    int* __restrict__ pnp, int P, int G, int PT) {
  int b = blockIdx.x / PT, tile = blockIdx.x % PT;
  int tid = threadIdx.x;
  int p = tile * 256 + tid;

  __shared__ float st[128 * 15];
  __shared__ unsigned hist[1024];
  __shared__ double rs[16];
  __shared__ int ri[4];

  for (int i = tid; i < G * 15; i += 256) st[i] = targets[(size_t)b * G * 15 + i];
  for (int i = tid; i < 1024; i += 256) hist[i] = 0;
  __syncthreads();

  double ll = 0, llm = 0, lc = 0, ms = 0;
  int np = 0;
  if (p < P) {
    size_t idx = (size_t)b * P + p;
    int av = anyv[b];
    float ov = bto[idx];
    int ti = bti[idx];
    bool pos = av && (ov >= 0.35f);

    float2 c = ((const float2*)conf)[idx];
    float mx = fmaxf(c.x, c.y);
    float d = fabsf(c.x - c.y);
    float lse = mx + logf(1.f + expf(-d));  // == mx+log(exp(cx-mx)+exp(cy-mx))
    float ce = lse - (pos ? c.y : c.x);
    float mv = pos ? 0.f : ce;
    mine[idx] = mv;
    ms = (double)mv;
    atomicAdd(&hist[__float_as_uint(mv) >> 21], 1u);

    if (pos) {
      np = 1;
      lc = (double)ce;
      float4 pr = ((const float4*)priors)[p];
      const float* t = st + ti * 15;
      float rz = 1.f / pr.z, rw = 1.f / pr.w;
      float rdx = 10.f * rz, rdy = 10.f * rw;  // 1/(0.1*w), 1/(0.1*h)
      float gx = ((t[0] + t[2]) * 0.5f - pr.x) * rdx;
      float gy = ((t[1] + t[3]) * 0.5f - pr.y) * rdy;
      float gw = logf((t[2] - t[0]) * rz) * 5.0f;
      float gh = logf((t[3] - t[1]) * rw) * 5.0f;
      float4 ld = ((const float4*)loc)[idx];
      ll = (double)(sl1(ld.x - gx) + sl1(ld.y - gy) + sl1(ld.z - gw) +
                    sl1(ld.w - gh));
      const float2* lmd = (const float2*)lm + idx * 5;
      float s = 0.f;
#pragma unroll
      for (int j = 0; j < 5; ++j) {
        float2 lv = lmd[j];
        float ex = (t[4 + 2 * j] - pr.x) * rdx;
        float ey = (t[5 + 2 * j] - pr.y) * rdy;
        s += sl1(lv.x - ex) + sl1(lv.y - ey);
      }
      llm = (double)s;
    }
  }

  ll = dwave(ll);
  llm = dwave(llm);
  lc = dwave(lc);
  ms = dwave(ms);
#pragma unroll
  for (int o = 32; o; o >>= 1) np += __shfl_down(np, o);
  int lane = tid & 63, wid = tid >> 6;
  if (lane == 0) {
    rs[wid] = ll; rs[4 + wid] = llm; rs[8 + wid] = lc; rs[12 + wid] = ms;
    ri[wid] = np;
  }
  __syncthreads();
  if (tid == 0) {
    pll[blockIdx.x] = rs[0] + rs[1] + rs[2] + rs[3];
    pllm[blockIdx.x] = rs[4] + rs[5] + rs[6] + rs[7];
    plc[blockIdx.x] = rs[8] + rs[9] + rs[10] + rs[11];
    msum[blockIdx.x] = rs[12] + rs[13] + rs[14] + rs[15];
    pnp[blockIdx.x] = ri[0] + ri[1] + ri[2] + ri[3];
  }
  for (int i = tid; i < 1024; i += 256)
    if (hist[i]) atomicAdd(&h1[(size_t)b * 1024 + i], hist[i]);
}

// per-b tail (B blocks x 1024): npos/msum reduce -> fast path or 3-pass
// radix; then last-of-B blocks (counter) reduces partials and writes out.
__global__ __launch_bounds__(1024) void k_tail(
    const unsigned* __restrict__ h1, const int* __restrict__ pnp,
    const double* __restrict__ msum, const float* __restrict__ mine,
    const double* __restrict__ pll, const double* __restrict__ pllm,
    const double* __restrict__ plc, int* __restrict__ num_pos,
    double* __restrict__ pfs_b, int* __restrict__ ctr,
    float* __restrict__ out, int P, int PT, int NBm, int B) {
  int b = blockIdx.x, tid = threadIdx.x;
  __shared__ double sm[1024];
  __shared__ int sn[1024];
  __shared__ unsigned S[1024];
  __shared__ unsigned hs[2048];
  __shared__ int spf1, sk1, spf21, sk2;
  __shared__ unsigned stb;
  __shared__ double stie;
  __shared__ double rs[16];
  __shared__ int slast;

  int n = 0;
  double m = 0;
  for (int i = tid; i < PT; i += 1024) { n += pnp[b * PT + i]; m += msum[b * PT + i]; }
  sn[tid] = n; sm[tid] = m;
  __syncthreads();
  for (int off = 512; off; off >>= 1) {
    if (tid < off) { sn[tid] += sn[tid + off]; sm[tid] += sm[tid + off]; }
    __syncthreads();
  }
  int npos = sn[0];
  if (tid == 0) num_pos[b] = npos;

  long long k = 7LL * (long long)npos;
  long long cap = P - 1;
  double result = 0.0;
  if (k > 0 && k >= cap) {
    result = sm[0];  // FAST PATH: all negatives selected
  } else if (k > 0) {
    const float* mrow = mine + (size_t)b * P;
    // pass 0: top-11-bit select from h1 (1024 bins, 1/thread)
    {
      unsigned own = h1[(size_t)b * 1024 + tid];
      S[tid] = own;
      __syncthreads();
      for (int off = 1; off < 1024; off <<= 1) {
        unsigned add = (tid + off < 1024) ? S[tid + off] : 0;
        __syncthreads();
        S[tid] += add;
        __syncthreads();
      }
      int cnt = __syncthreads_count((long long)S[tid] >= k);
      int seg = cnt - 1;
      if (tid == seg) {
        long long cum = (seg + 1 < 1024) ? (long long)S[seg + 1] : 0;
        spf1 = seg;
        sk1 = (int)(k - cum);
      }
    }
    __syncthreads();
    int pf = spf1;

    // pass A: bits[20:10] within top bin (2048 bins)
    hs[tid] = 0; hs[tid + 1024] = 0;
    __syncthreads();
    for (int base = 0; base < P; base += 4096) {
      int i0 = base + tid;
      int i1 = i0 + 1024, i2 = i0 + 2048, i3 = i0 + 3072;
      unsigned b0 = (i0 < P) ? __float_as_uint(mrow[i0]) : 0u;
      unsigned b1 = (i1 < P) ? __float_as_uint(mrow[i1]) : 0u;
      unsigned b2 = (i2 < P) ? __float_as_uint(mrow[i2]) : 0u;
      unsigned b3 = (i3 < P) ? __float_as_uint(mrow[i3]) : 0u;
      if (i0 < P && (int)(b0 >> 21) == pf) atomicAdd(&hs[(b0 >> 10) & 2047], 1u);
      if (i1 < P && (int)(b1 >> 21) == pf) atomicAdd(&hs[(b1 >> 10) & 2047], 1u);
      if (i2 < P && (int)(b2 >> 21) == pf) atomicAdd(&hs[(b2 >> 10) & 2047], 1u);
      if (i3 < P && (int)(b3 >> 21) == pf) atomicAdd(&hs[(b3 >> 10) & 2047], 1u);
    }
    __syncthreads();
    {
      unsigned h0 = hs[tid * 2], h1v = hs[tid * 2 + 1];
      S[tid] = h0 + h1v;
      __syncthreads();
      for (int off = 1; off < 1024; off <<= 1) {
        unsigned add = (tid + off < 1024) ? S[tid + off] : 0;
        __syncthreads();
        S[tid] += add;
        __syncthreads();
      }
      long long kk = (long long)sk1;
      int cnt = __syncthreads_count((long long)S[tid] >= kk);
      int seg = cnt - 1;
      if (tid == seg) {
        long long cum = (seg + 1 < 1024) ? (long long)S[seg + 1] : 0;
        int bin = seg * 2;
        if (cum + h1v >= kk) bin = seg * 2 + 1;
        else cum += h1v;
        spf21 = (pf << 11) | bin;
        sk2 = (int)(kk - cum);
      }
    }
    __syncthreads();
    int pf21 = spf21;

    // pass B: bits[9:0] (1024 bins)
    hs[tid] = 0;
    __syncthreads();
    for (int base = 0; base < P; base += 4096) {
      int i0 = base + tid;
      int i1 = i0 + 1024, i2 = i0 + 2048, i3 = i0 + 3072;
      unsigned b0 = (i0 < P) ? __float_as_uint(mrow[i0]) : 0u;
      unsigned b1 = (i1 < P) ? __float_as_uint(mrow[i1]) : 0u;
      unsigned b2 = (i2 < P) ? __float_as_uint(mrow[i2]) : 0u;
      unsigned b3 = (i3 < P) ? __float_as_uint(mrow[i3]) : 0u;
      if (i0 < P && (int)(b0 >> 10) == pf21) atomicAdd(&hs[b0 & 1023], 1u);
      if (i1 < P && (int)(b1 >> 10) == pf21) atomicAdd(&hs[b1 & 1023], 1u);
      if (i2 < P && (int)(b2 >> 10) == pf21) atomicAdd(&hs[b2 & 1023], 1u);
      if (i3 < P && (int)(b3 >> 10) == pf21) atomicAdd(&hs[b3 & 1023], 1u);
    }
    __syncthreads();
    {
      unsigned own = hs[tid];
      S[tid] = own;
      __syncthreads();
      for (int off = 1; off < 1024; off <<= 1) {
        unsigned add = (tid + off < 1024) ? S[tid + off] : 0;
        __syncthreads();
        S[tid] += add;
        __syncthreads();
      }
      long long kk = (long long)sk2;
      int cnt = __syncthreads_count((long long)S[tid] >= kk);
      int seg = cnt - 1;
      if (tid == seg) {
        long long cum = (seg + 1 < 1024) ? (long long)S[seg + 1] : 0;
        unsigned tb = ((unsigned)pf21 << 10) | (unsigned)seg;
        stb = tb;
        stie = (double)(kk - cum) * (double)__uint_as_float(tb);
      }
    }
    __syncthreads();

    // pass C: sum strictly above threshold + tie contribution
    unsigned tb = stb;
    double v = 0.0;
    for (int base = 0; base < P; base += 4096) {
      int i0 = base + tid;
      int i1 = i0 + 1024, i2 = i0 + 2048, i3 = i0 + 3072;
      unsigned b0 = (i0 < P) ? __float_as_uint(mrow[i0]) : 0u;
      unsigned b1 = (i1 < P) ? __float_as_uint(mrow[i1]) : 0u;
      unsigned b2 = (i2 < P) ? __float_as_uint(mrow[i2]) : 0u;
      unsigned b3 = (i3 < P) ? __float_as_uint(mrow[i3]) : 0u;
      if (b0 > tb) v += (double)__uint_as_float(b0);
      if (b1 > tb) v += (double)__uint_as_float(b1);
      if (b2 > tb) v += (double)__uint_as_float(b2);
      if (b3 > tb) v += (double)__uint_as_float(b3);
    }
    v = dwave(v);
    int lane = tid & 63, wid = tid >> 6;
    if (lane == 0) rs[wid] = v;
    __syncthreads();
    if (tid == 0) {
      double t = 0;
      for (int i = 0; i < 16; ++i) t += rs[i];
      result = t + stie;
    }
  }
  if (tid == 0) pfs_b[b] = result;

  // ---- completion counter: last block does the final reduction ----
  __syncthreads();
  if (tid == 0) {
    __threadfence();
    slast = (atomicAdd(ctr, 1) == B - 1) ? 1 : 0;
  }
  __syncthreads();
  if (!slast) return;
  __threadfence();

  double a = 0, c = 0, d2 = 0, f = 0, n2 = 0;
  for (int i = tid; i < NBm; i += 1024) { a += pll[i]; c += pllm[i]; d2 += plc[i]; }
  for (int i = tid; i < B; i += 1024) { f += pfs_b[i]; n2 += (double)num_pos[i]; }
  a = dwave(a); c = dwave(c); d2 = dwave(d2); f = dwave(f); n2 = dwave(n2);
  __shared__ double fr[5 * 16];
  int lane = tid & 63, wid = tid >> 6;
  if (lane == 0) {
    fr[wid] = a; fr[16 + wid] = c; fr[32 + wid] = d2;
    fr[48 + wid] = f; fr[64 + wid] = n2;
  }
  __syncthreads();
  if (tid == 0) {
    double A = 0, C = 0, D = 0, F = 0, N = 0;
    for (int i = 0; i < 16; ++i) {
      A += fr[i]; C += fr[16 + i]; D += fr[32 + i];
      F += fr[48 + i]; N += fr[64 + i];
    }
    if (N < 1.0) N = 1.0;
    out[0] = (float)(A / N);
    out[1] = (float)((D + F) / N);
    out[2] = (float)(C / N);
  }
}

extern "C" void kernel_launch(void* const* d_in, const int* in_sizes, int n_in,
                              void* d_out, int out_size, void* d_ws,
                              size_t ws_size, hipStream_t stream) {
  const float* loc = (const float*)d_in[0];
  const float* conf = (const float*)d_in[1];
  const float* lm = (const float*)d_in[2];
  const float* priors = (const float*)d_in[3];
  const float* targets = (const float*)d_in[4];

  int P = in_sizes[3] / 4;
  int B = in_sizes[0] / (4 * P);
  int G = in_sizes[4] / (15 * B);
  int PT = (P + 255) / 256;
  int PTI = (P + 256 * PPI - 1) / (256 * PPI);
  int NBm = B * PT;
  int NGC = (G + GC - 1) / GC;
  int PC = 8;

  char* w = (char*)d_ws;
  size_t off = 0;
  // ---- zeroed region ----
  unsigned long long* bp = (unsigned long long*)(w + off);
  off += (size_t)B * G * 8;
  double* pfs_b = (double*)(w + off);
  off += (size_t)B * 8;
  int* ctrl = (int*)(w + off);
  off += (size_t)(2 * B + 2) * 4;
  int* anyv = ctrl;
  int* num_pos = ctrl + B;
  int* ctr = ctrl + 2 * B;
  off = (off + 7) & ~(size_t)7;
  unsigned* h1 = (unsigned*)(w + off);
  off += (size_t)B * 1024 * 4;
  size_t clear_bytes = off;
  // ---- non-zeroed region (written unconditionally) ----
  off = (off + 255) & ~(size_t)255;
  float* bto = (float*)(w + off);
  off += (size_t)B * P * 4;
  int* bti = (int*)(w + off);
  off += (size_t)B * P * 4;
  float* mine = (float*)(w + off);
  off += (size_t)B * P * 4;
  double* pll = (double*)(w + off);
  off += (size_t)NBm * 8;
  double* pllm = (double*)(w + off);
  off += (size_t)NBm * 8;
  double* plc = (double*)(w + off);
  off += (size_t)NBm * 8;
  double* msum = (double*)(w + off);
  off += (size_t)NBm * 8;
  int* pnp = (int*)(w + off);
  off += (size_t)NBm * 4;

  hipMemsetAsync(d_ws, 0, clear_bytes, stream);

  k_iou<<<B * PTI, 256, 0, stream>>>(priors, targets, bto, bti, P, G, PTI);
  k_bp<<<B * NGC * PC, 256, 0, stream>>>(priors, targets, bp, P, G, NGC, PC);
  k_scatter<<<B, G, 0, stream>>>(bp, bto, bti, anyv, P, G);
  k_main<<<B * PT, 256, 0, stream>>>(loc, conf, lm, priors, targets, bto, bti,
                                     anyv, mine, h1, pll, pllm, plc, msum, pnp,
                                     P, G, PT);
  k_tail<<<B, 1024, 0, stream>>>(h1, pnp, msum, mine, pll, pllm, plc, num_pos,
                                 pfs_b, ctr, (float*)d_out, P, PT, NBm, B);
}

// Round 13
// 177.934 us; speedup vs baseline: 1.0949x; 1.0949x over previous
//
#include <hip/hip_runtime.h>
#include <stdint.h>

// MultiBoxLoss B=16, P=43008, G=128.
// R13: k_main eliminated — per-prior loss work fused into k_mm's iou role
//      (uses in-register pre-scatter ov/ti; conf/loc/lm read once). Forced
//      entries (<=G per b) corrected by k_fix delta kernel (exact doubles,
//      identical float paths). anyv==0 handled by gating in k_tail. h1 gone;
//      slow path (never taken in practice) builds its own hist in k_tail.
//      5 dispatches: memset(16KB), k_mm, k_fix, k_tail, k_fin.

#define GC 8    // GTs per bp-role block
#define PPI 4   // priors/thread in iou role

__device__ __forceinline__ float sl1(float x) {
  float a = fabsf(x);
  return a < 1.f ? 0.5f * a * a : a - 0.5f;
}

__device__ __forceinline__ double dwave(double v) {
#pragma unroll
  for (int o = 32; o; o >>= 1) v += __shfl_down(v, o);
  return v;
}

__global__ __launch_bounds__(256) void k_mm(
    const float* __restrict__ priors, const float* __restrict__ targets,
    const float* __restrict__ loc, const float* __restrict__ conf,
    const float* __restrict__ lm, float* __restrict__ bto,
    int* __restrict__ bti, unsigned long long* __restrict__ bp,
    float* __restrict__ mine, double* __restrict__ pll,
    double* __restrict__ pllm, double* __restrict__ plc,
    double* __restrict__ msum, int* __restrict__ pnp, int P, int G, int NIOU,
    int PTI, int NGC, int PC) {
  int tid = threadIdx.x;
  __shared__ char smem[16384];  // bp: sred(16KB); iou: st(7.5KB)+rs+ri
  __shared__ float4 sgt[128];
  __shared__ float sga[128];

  if ((int)blockIdx.x < NIOU) {
    // ---- iou role: best-truth per prior + full per-prior loss work ----
    float* st = (float*)smem;                  // 128*15 floats
    double* rs = (double*)(smem + 7680);       // 16 doubles
    int* ri = (int*)(smem + 7808);             // 4 ints
    int b = blockIdx.x / PTI, tile = blockIdx.x % PTI;
    int base = tile * (256 * PPI);
    for (int i = tid; i < G * 15; i += 256)
      st[i] = targets[(size_t)b * G * 15 + i];
    for (int g = tid; g < G; g += 256) {
      const float* t = targets + ((size_t)b * G + g) * 15;
      float x1 = t[0], y1 = t[1], x2 = t[2], y2 = t[3];
      sgt[g] = make_float4(x1, y1, x2, y2);
      sga[g] = (x2 - x1) * (y2 - y1);
    }
    __syncthreads();

    float px1[PPI], py1[PPI], px2[PPI], py2[PPI], pa[PPI];
    float bi[PPI], sb[PPI];
    int bidx[PPI];
#pragma unroll
    for (int k = 0; k < PPI; ++k) {
      int p = base + tid + k * 256;
      int pl = p < P ? p : P - 1;
      float4 pr = ((const float4*)priors)[pl];
      px1[k] = pr.x - pr.z * 0.5f; py1[k] = pr.y - pr.w * 0.5f;
      px2[k] = pr.x + pr.z * 0.5f; py2[k] = pr.y + pr.w * 0.5f;
      pa[k] = pr.z * pr.w;
      bi[k] = 0.f; sb[k] = 1.f; bidx[k] = 0;
    }

#define IOU_BODY(T, A, GG)                                                 \
  {                                                                        \
    float iw = fminf(T.z, px2[k]) - fmaxf(T.x, px1[k]);                    \
    float ih = fminf(T.w, py2[k]) - fmaxf(T.y, py1[k]);                    \
    float inter = fmaxf(iw, 0.f) * ih;                                     \
    float S = A + pa[k];                                                   \
    if (inter * sb[k] > bi[k] * S) { bi[k] = inter; sb[k] = S; bidx[k] = GG; } \
  }
    for (int g = 0; g < G; g += 4) {
      float4 T0 = sgt[g], T1 = sgt[g + 1], T2 = sgt[g + 2], T3 = sgt[g + 3];
      float A0 = sga[g], A1 = sga[g + 1], A2 = sga[g + 2], A3 = sga[g + 3];
#pragma unroll
      for (int k = 0; k < PPI; ++k) {
        IOU_BODY(T0, A0, g)
        IOU_BODY(T1, A1, g + 1)
        IOU_BODY(T2, A2, g + 2)
        IOU_BODY(T3, A3, g + 3)
      }
    }
#undef IOU_BODY

    // ---- main phase (pre-scatter ov/ti; k_fix corrects forced entries) ----
    double ll = 0, llm = 0, lc = 0, ms = 0;
    int np = 0;
#pragma unroll
    for (int k = 0; k < PPI; ++k) {
      int p = base + tid + k * 256;
      if (p < P) {
        size_t idx = (size_t)b * P + p;
        float ov = bi[k] / (sb[k] - bi[k]);
        int ti = bidx[k];
        bto[idx] = ov;
        bti[idx] = ti;
        bool pos = ov >= 0.35f;
        float2 c = ((const float2*)conf)[idx];
        float mx = fmaxf(c.x, c.y);
        float dd = fabsf(c.x - c.y);
        float lse = mx + logf(1.f + expf(-dd));
        float ce = lse - (pos ? c.y : c.x);
        float mv = pos ? 0.f : ce;
        mine[idx] = mv;
        ms += (double)mv;
        if (pos) {
          np++;
          lc += (double)ce;
          float4 pr = ((const float4*)priors)[p];
          const float* t = st + ti * 15;
          float rz = 1.f / pr.z, rw = 1.f / pr.w;
          float rdx = 10.f * rz, rdy = 10.f * rw;
          float gx = ((t[0] + t[2]) * 0.5f - pr.x) * rdx;
          float gy = ((t[1] + t[3]) * 0.5f - pr.y) * rdy;
          float gw = logf((t[2] - t[0]) * rz) * 5.0f;
          float gh = logf((t[3] - t[1]) * rw) * 5.0f;
          float4 ld = ((const float4*)loc)[idx];
          ll += (double)(sl1(ld.x - gx) + sl1(ld.y - gy) + sl1(ld.z - gw) +
                         sl1(ld.w - gh));
          const float2* lmd = (const float2*)lm + idx * 5;
          float s = 0.f;
#pragma unroll
          for (int j = 0; j < 5; ++j) {
            float2 lv = lmd[j];
            float ex = (t[4 + 2 * j] - pr.x) * rdx;
            float ey = (t[5 + 2 * j] - pr.y) * rdy;
            s += sl1(lv.x - ex) + sl1(lv.y - ey);
          }
          llm += (double)s;
        }
      }
    }

    ll = dwave(ll); llm = dwave(llm); lc = dwave(lc); ms = dwave(ms);
#pragma unroll
    for (int o = 32; o; o >>= 1) np += __shfl_down(np, o);
    int lane = tid & 63, wid = tid >> 6;
    if (lane == 0) {
      rs[wid] = ll; rs[4 + wid] = llm; rs[8 + wid] = lc; rs[12 + wid] = ms;
      ri[wid] = np;
    }
    __syncthreads();
    if (tid == 0) {
      pll[blockIdx.x] = rs[0] + rs[1] + rs[2] + rs[3];
      pllm[blockIdx.x] = rs[4] + rs[5] + rs[6] + rs[7];
      plc[blockIdx.x] = rs[8] + rs[9] + rs[10] + rs[11];
      msum[blockIdx.x] = rs[12] + rs[13] + rs[14] + rs[15];
      pnp[blockIdx.x] = ri[0] + ri[1] + ri[2] + ri[3];
    }
  } else {
    // ---- bp role: per-GT best-prior over a P-chunk ----
    unsigned long long* sred = (unsigned long long*)smem;  // GC*256
    int bc = blockIdx.x - NIOU;
    int pc = bc % PC;
    int gcb = (bc / PC) % NGC;
    int b = bc / (PC * NGC);
    int g0 = gcb * GC;

    if (tid < GC) {
      int g = g0 + tid;
      float4 v = make_float4(0.f, 0.f, 0.f, 0.f);
      if (g < G) {
        const float* t = targets + ((size_t)b * G + g) * 15;
        v = make_float4(t[0], t[1], t[2], t[3]);
      }
      sgt[tid] = v;
    }
    __syncthreads();

    float gx1[GC], gy1[GC], gx2[GC], gy2[GC], ga[GC];
#pragma unroll
    for (int j = 0; j < GC; ++j) {
      float4 T = sgt[j];
      gx1[j] = T.x; gy1[j] = T.y; gx2[j] = T.z; gy2[j] = T.w;
      ga[j] = (T.z - T.x) * (T.w - T.y);
    }

    int chunk = (P + PC - 1) / PC;
    int ps = pc * chunk;
    int pe = ps + chunk; if (pe > P) pe = P;
    int count = pe - ps;

    float bi[GC], sb[GC];
    unsigned bpp[GC];
#pragma unroll
    for (int j = 0; j < GC; ++j) { bi[j] = 0.f; sb[j] = 1.f; bpp[j] = (unsigned)(ps + tid); }

#define BP_BODY(X1, Y1, X2, Y2, AR, PP)                                     \
  {                                                                         \
    float iw = fminf(gx2[j], X2) - fmaxf(gx1[j], X1);                       \
    float ih = fminf(gy2[j], Y2) - fmaxf(gy1[j], Y1);                       \
    float inter = fmaxf(iw, 0.f) * ih;                                      \
    float S = ga[j] + AR;                                                   \
    if (inter * sb[j] > bi[j] * S) { bi[j] = inter; sb[j] = S; bpp[j] = (unsigned)PP; } \
  }
    for (int i = tid; i < count; i += 1024) {
      int p0 = ps + i;
      int i1 = i + 256, i2 = i + 512, i3 = i + 768;
      int p1 = (i1 < count) ? ps + i1 : p0;
      int p2 = (i2 < count) ? ps + i2 : p0;
      int p3 = (i3 < count) ? ps + i3 : p0;
      float4 q0 = ((const float4*)priors)[p0];
      float4 q1 = ((const float4*)priors)[p1];
      float4 q2 = ((const float4*)priors)[p2];
      float4 q3 = ((const float4*)priors)[p3];
      float ax1 = q0.x - q0.z * 0.5f, ay1 = q0.y - q0.w * 0.5f;
      float ax2 = q0.x + q0.z * 0.5f, ay2 = q0.y + q0.w * 0.5f;
      float aa = q0.z * q0.w;
      float bx1 = q1.x - q1.z * 0.5f, by1 = q1.y - q1.w * 0.5f;
      float bx2 = q1.x + q1.z * 0.5f, by2 = q1.y + q1.w * 0.5f;
      float ba = q1.z * q1.w;
      float cx1 = q2.x - q2.z * 0.5f, cy1 = q2.y - q2.w * 0.5f;
      float cx2 = q2.x + q2.z * 0.5f, cy2 = q2.y + q2.w * 0.5f;
      float ca = q2.z * q2.w;
      float dx1 = q3.x - q3.z * 0.5f, dy1 = q3.y - q3.w * 0.5f;
      float dx2 = q3.x + q3.z * 0.5f, dy2 = q3.y + q3.w * 0.5f;
      float da = q3.z * q3.w;
#pragma unroll
      for (int j = 0; j < GC; ++j) {
        BP_BODY(ax1, ay1, ax2, ay2, aa, p0)
        BP_BODY(bx1, by1, bx2, by2, ba, p1)
        BP_BODY(cx1, cy1, cx2, cy2, ca, p2)
        BP_BODY(dx1, dy1, dx2, dy2, da, p3)
      }
    }
#undef BP_BODY

#pragma unroll
    for (int j = 0; j < GC; ++j) {
      float iou = bi[j] / (sb[j] - bi[j]);
      unsigned long long pk =
          ((unsigned long long)__float_as_uint(iou) << 32) | (unsigned)(~bpp[j]);
      sred[j * 256 + tid] = pk;
    }
    __syncthreads();
    {
      int j = tid >> 5, s = tid & 31;
      unsigned long long m = sred[j * 256 + s];
#pragma unroll
      for (int t = 1; t < 8; ++t) {
        unsigned long long v = sred[j * 256 + s + t * 32];
        if (v > m) m = v;
      }
      __syncthreads();
      sred[j * 256 + s] = m;
    }
    __syncthreads();
    if (tid < GC) {
      unsigned long long m = sred[tid * 256];
      for (int s = 1; s < 32; ++s) {
        unsigned long long v = sred[tid * 256 + s];
        if (v > m) m = v;
      }
      int g = g0 + tid;
      if (g < G) atomicMax(&bp[(size_t)b * G + g], m);
    }
  }
}

// per-b fixup of forced entries: last-dup-wins, ti:=g always, ov:=2 iff valid.
// Computes exact delta contributions (identical float paths as k_mm).
__global__ void k_fix(const unsigned long long* __restrict__ bp,
                      const float* __restrict__ bto, const int* __restrict__ bti,
                      const float* __restrict__ conf, const float* __restrict__ loc,
                      const float* __restrict__ lm, const float* __restrict__ priors,
                      const float* __restrict__ targets, float* __restrict__ mine,
                      int* __restrict__ anyv, double* __restrict__ dacc,
                      int* __restrict__ dnpb, int P, int G) {
  int b = blockIdx.x, g = threadIdx.x;
  __shared__ unsigned spp[128];
  __shared__ double sd[128 * 4];
  __shared__ int si[128];

  unsigned long long m = bp[(size_t)b * G + g];
  unsigned pp = ~(unsigned)m;
  float val = __uint_as_float((unsigned)(m >> 32));
  spp[g] = pp;
  bool valid = val >= 0.2f;
  int av = __syncthreads_or(valid ? 1 : 0);
  if (g == 0) anyv[b] = av;

  bool win = true;
  for (int g2 = g + 1; g2 < G; ++g2)
    if (spp[g2] == pp) { win = false; break; }

  double dll = 0, dllm = 0, dlc = 0, dms = 0;
  int dnp = 0;
  if (win) {
    size_t idx = (size_t)b * P + pp;
    float ov_o = bto[idx];
    int ti_o = bti[idx];
    float ov_n = valid ? 2.0f : ov_o;
    int ti_n = g;
    bool pos_o = ov_o >= 0.35f, pos_n = ov_n >= 0.35f;

    float2 c = ((const float2*)conf)[idx];
    float mx = fmaxf(c.x, c.y);
    float dd = fabsf(c.x - c.y);
    float lse = mx + logf(1.f + expf(-dd));
    float ce_o = lse - (pos_o ? c.y : c.x);
    float ce_n = lse - (pos_n ? c.y : c.x);
    float mv_o = mine[idx];
    float mv_n = pos_n ? 0.f : ce_n;
    if (mv_n != mv_o) mine[idx] = mv_n;
    dms = (double)mv_n - (double)mv_o;
    dnp = (pos_n ? 1 : 0) - (pos_o ? 1 : 0);
    dlc = (pos_n ? (double)ce_n : 0.0) - (pos_o ? (double)ce_o : 0.0);

    if (pos_o || pos_n) {
      float4 pr = ((const float4*)priors)[pp];
      float rz = 1.f / pr.z, rw = 1.f / pr.w;
      float rdx = 10.f * rz, rdy = 10.f * rw;
      float4 ld = ((const float4*)loc)[idx];
      const float2* lmd = (const float2*)lm + idx * 5;
      float2 lv[5];
#pragma unroll
      for (int j = 0; j < 5; ++j) lv[j] = lmd[j];
      for (int pass = 0; pass < 2; ++pass) {
        bool act = pass ? pos_n : pos_o;
        int ti = pass ? ti_n : ti_o;
        if (!act) continue;
        const float* t = targets + ((size_t)b * G + ti) * 15;
        float gx = ((t[0] + t[2]) * 0.5f - pr.x) * rdx;
        float gy = ((t[1] + t[3]) * 0.5f - pr.y) * rdy;
        float gw = logf((t[2] - t[0]) * rz) * 5.0f;
        float gh = logf((t[3] - t[1]) * rw) * 5.0f;
        double l = (double)(sl1(ld.x - gx) + sl1(ld.y - gy) +
                            sl1(ld.z - gw) + sl1(ld.w - gh));
        float s = 0.f;
#pragma unroll
        for (int j = 0; j < 5; ++j) {
          float ex = (t[4 + 2 * j] - pr.x) * rdx;
          float ey = (t[5 + 2 * j] - pr.y) * rdy;
          s += sl1(lv[j].x - ex) + sl1(lv[j].y - ey);
        }
        if (pass) { dll += l; dllm += (double)s; }
        else { dll -= l; dllm -= (double)s; }
      }
    }
  }
  sd[g] = dll; sd[128 + g] = dllm; sd[256 + g] = dlc; sd[384 + g] = dms;
  si[g] = dnp;
  __syncthreads();
  for (int off = 64; off; off >>= 1) {
    if (g < off) {
      sd[g] += sd[g + off]; sd[128 + g] += sd[128 + g + off];
      sd[256 + g] += sd[256 + g + off]; sd[384 + g] += sd[384 + g + off];
      si[g] += si[g + off];
    }
    __syncthreads();
  }
  if (g == 0) {
    dacc[b * 4 + 0] = sd[0]; dacc[b * 4 + 1] = sd[128];
    dacc[b * 4 + 2] = sd[256]; dacc[b * 4 + 3] = sd[384];
    dnpb[b] = si[0];
  }
}

// per-b tail: reduce partials + deltas, gate by anyv, fast/slow path.
__global__ __launch_bounds__(1024) void k_tail(
    const int* __restrict__ pnp, const double* __restrict__ msum,
    const double* __restrict__ pll, const double* __restrict__ pllm,
    const double* __restrict__ plc, const double* __restrict__ dacc,
    const int* __restrict__ dnpb, const int* __restrict__ anyv,
    const float* __restrict__ mine, int* __restrict__ num_pos,
    double* __restrict__ pllb, double* __restrict__ pllmb,
    double* __restrict__ plcb, double* __restrict__ pfs_b, int P, int PTI) {
  int b = blockIdx.x, tid = threadIdx.x;
  __shared__ double rs[16 * 5];
  __shared__ int ris[16];
  __shared__ unsigned S[1024];
  __shared__ unsigned hs[2048];
  __shared__ int spf1, sk1, spf21, sk2;
  __shared__ unsigned stb;
  __shared__ double stie;

  double a = 0, cc = 0, d = 0, ms = 0;
  int n = 0;
  for (int i = tid; i < PTI; i += 1024) {
    int ix = b * PTI + i;
    a += pll[ix]; cc += pllm[ix]; d += plc[ix]; ms += msum[ix]; n += pnp[ix];
  }
  a = dwave(a); cc = dwave(cc); d = dwave(d); ms = dwave(ms);
#pragma unroll
  for (int o = 32; o; o >>= 1) n += __shfl_down(n, o);
  int lane = tid & 63, wid = tid >> 6;
  if (lane == 0) {
    rs[wid] = a; rs[16 + wid] = cc; rs[32 + wid] = d; rs[48 + wid] = ms;
    ris[wid] = n;
  }
  __syncthreads();
  int npos = 0;
  double A = 0, C = 0, D = 0, MS = 0;
  if (tid == 0) {
    for (int i = 0; i < 16; ++i) {
      A += rs[i]; C += rs[16 + i]; D += rs[32 + i]; MS += rs[48 + i];
      npos += ris[i];
    }
    A += dacc[b * 4 + 0]; C += dacc[b * 4 + 1]; D += dacc[b * 4 + 2];
    MS += dacc[b * 4 + 3];
    npos += dnpb[b];
    if (!anyv[b]) { A = 0; C = 0; D = 0; npos = 0; }
    num_pos[b] = npos;
    pllb[b] = A; pllmb[b] = C; plcb[b] = D;
    ris[0] = npos;
    rs[48] = MS;  // reuse slot for gated decision below
  }
  __syncthreads();
  npos = ris[0];
  MS = rs[48];

  long long k = 7LL * (long long)npos;
  long long cap = P - 1;
  if (k <= 0) {
    if (tid == 0) pfs_b[b] = 0.0;
    return;
  }
  if (k >= cap) {
    if (tid == 0) pfs_b[b] = MS;  // FAST PATH: all negatives selected
    return;
  }

  const float* mrow = mine + (size_t)b * P;
  // pass 0: hist over bits[31:21] (mine>=0 -> 1024 bins), then select
  hs[tid] = 0;
  __syncthreads();
  for (int base = 0; base < P; base += 4096) {
    int i0 = base + tid;
    int i1 = i0 + 1024, i2 = i0 + 2048, i3 = i0 + 3072;
    unsigned b0 = (i0 < P) ? __float_as_uint(mrow[i0]) : 0xFFFFFFFFu;
    unsigned b1 = (i1 < P) ? __float_as_uint(mrow[i1]) : 0xFFFFFFFFu;
    unsigned b2 = (i2 < P) ? __float_as_uint(mrow[i2]) : 0xFFFFFFFFu;
    unsigned b3 = (i3 < P) ? __float_as_uint(mrow[i3]) : 0xFFFFFFFFu;
    if (b0 != 0xFFFFFFFFu) atomicAdd(&hs[b0 >> 21], 1u);
    if (b1 != 0xFFFFFFFFu) atomicAdd(&hs[b1 >> 21], 1u);
    if (b2 != 0xFFFFFFFFu) atomicAdd(&hs[b2 >> 21], 1u);
    if (b3 != 0xFFFFFFFFu) atomicAdd(&hs[b3 >> 21], 1u);
  }
  __syncthreads();
  {
    S[tid] = hs[tid];
    __syncthreads();
    for (int off = 1; off < 1024; off <<= 1) {
      unsigned add = (tid + off < 1024) ? S[tid + off] : 0;
      __syncthreads();
      S[tid] += add;
      __syncthreads();
    }
    int cnt = __syncthreads_count((long long)S[tid] >= k);
    int seg = cnt - 1;
    if (tid == seg) {
      long long cum = (seg + 1 < 1024) ? (long long)S[seg + 1] : 0;
      spf1 = seg;
      sk1 = (int)(k - cum);
    }
  }
  __syncthreads();
  int pf = spf1;

  // pass A: bits[20:10] within top bin (2048 bins)
  hs[tid] = 0; hs[tid + 1024] = 0;
  __syncthreads();
  for (int base = 0; base < P; base += 4096) {
    int i0 = base + tid;
    int i1 = i0 + 1024, i2 = i0 + 2048, i3 = i0 + 3072;
    unsigned b0 = (i0 < P) ? __float_as_uint(mrow[i0]) : 0u;
    unsigned b1 = (i1 < P) ? __float_as_uint(mrow[i1]) : 0u;
    unsigned b2 = (i2 < P) ? __float_as_uint(mrow[i2]) : 0u;
    unsigned b3 = (i3 < P) ? __float_as_uint(mrow[i3]) : 0u;
    if (i0 < P && (int)(b0 >> 21) == pf) atomicAdd(&hs[(b0 >> 10) & 2047], 1u);
    if (i1 < P && (int)(b1 >> 21) == pf) atomicAdd(&hs[(b1 >> 10) & 2047], 1u);
    if (i2 < P && (int)(b2 >> 21) == pf) atomicAdd(&hs[(b2 >> 10) & 2047], 1u);
    if (i3 < P && (int)(b3 >> 21) == pf) atomicAdd(&hs[(b3 >> 10) & 2047], 1u);
  }
  __syncthreads();
  {
    unsigned h0 = hs[tid * 2], h1v = hs[tid * 2 + 1];
    S[tid] = h0 + h1v;
    __syncthreads();
    for (int off = 1; off < 1024; off <<= 1) {
      unsigned add = (tid + off < 1024) ? S[tid + off] : 0;
      __syncthreads();
      S[tid] += add;
      __syncthreads();
    }
    long long kk = (long long)sk1;
    int cnt = __syncthreads_count((long long)S[tid] >= kk);
    int seg = cnt - 1;
    if (tid == seg) {
      long long cum = (seg + 1 < 1024) ? (long long)S[seg + 1] : 0;
      int bin = seg * 2;
      if (cum + h1v >= kk) bin = seg * 2 + 1;
      else cum += h1v;
      spf21 = (pf << 11) | bin;
      sk2 = (int)(kk - cum);
    }
  }
  __syncthreads();
  int pf21 = spf21;

  // pass B: bits[9:0] (1024 bins)
  hs[tid] = 0;
  __syncthreads();
  for (int base = 0; base < P; base += 4096) {
    int i0 = base + tid;
    int i1 = i0 + 1024, i2 = i0 + 2048, i3 = i0 + 3072;
    unsigned b0 = (i0 < P) ? __float_as_uint(mrow[i0]) : 0u;
    unsigned b1 = (i1 < P) ? __float_as_uint(mrow[i1]) : 0u;
    unsigned b2 = (i2 < P) ? __float_as_uint(mrow[i2]) : 0u;
    unsigned b3 = (i3 < P) ? __float_as_uint(mrow[i3]) : 0u;
    if (i0 < P && (int)(b0 >> 10) == pf21) atomicAdd(&hs[b0 & 1023], 1u);
    if (i1 < P && (int)(b1 >> 10) == pf21) atomicAdd(&hs[b1 & 1023], 1u);
    if (i2 < P && (int)(b2 >> 10) == pf21) atomicAdd(&hs[b2 & 1023], 1u);
    if (i3 < P && (int)(b3 >> 10) == pf21) atomicAdd(&hs[b3 & 1023], 1u);
  }
  __syncthreads();
  {
    S[tid] = hs[tid];
    __syncthreads();
    for (int off = 1; off < 1024; off <<= 1) {
      unsigned add = (tid + off < 1024) ? S[tid + off] : 0;
      __syncthreads();
      S[tid] += add;
      __syncthreads();
    }
    long long kk = (long long)sk2;
    int cnt = __syncthreads_count((long long)S[tid] >= kk);
    int seg = cnt - 1;
    if (tid == seg) {
      long long cum = (seg + 1 < 1024) ? (long long)S[seg + 1] : 0;
      unsigned tb = ((unsigned)pf21 << 10) | (unsigned)seg;
      stb = tb;
      stie = (double)(kk - cum) * (double)__uint_as_float(tb);
    }
  }
  __syncthreads();

  unsigned tb = stb;
  double v = 0.0;
  for (int base = 0; base < P; base += 4096) {
    int i0 = base + tid;
    int i1 = i0 + 1024, i2 = i0 + 2048, i3 = i0 + 3072;
    unsigned b0 = (i0 < P) ? __float_as_uint(mrow[i0]) : 0u;
    unsigned b1 = (i1 < P) ? __float_as_uint(mrow[i1]) : 0u;
    unsigned b2 = (i2 < P) ? __float_as_uint(mrow[i2]) : 0u;
    unsigned b3 = (i3 < P) ? __float_as_uint(mrow[i3]) : 0u;
    if (b0 > tb) v += (double)__uint_as_float(b0);
    if (b1 > tb) v += (double)__uint_as_float(b1);
    if (b2 > tb) v += (double)__uint_as_float(b2);
    if (b3 > tb) v += (double)__uint_as_float(b3);
  }
  v = dwave(v);
  if (lane == 0) rs[wid] = v;
  __syncthreads();
  if (tid == 0) {
    double t = 0;
    for (int i = 0; i < 16; ++i) t += rs[i];
    pfs_b[b] = t + stie;
  }
}

__global__ void k_fin(const double* __restrict__ pllb,
                      const double* __restrict__ pllmb,
                      const double* __restrict__ plcb,
                      const double* __restrict__ pfs_b,
                      const int* __restrict__ num_pos, float* __restrict__ out,
                      int B) {
  if (threadIdx.x == 0) {
    double A = 0, C = 0, D = 0, F = 0, N = 0;
    for (int i = 0; i < B; ++i) {
      A += pllb[i]; C += pllmb[i]; D += plcb[i]; F += pfs_b[i];
      N += (double)num_pos[i];
    }
    if (N < 1.0) N = 1.0;
    out[0] = (float)(A / N);
    out[1] = (float)((D + F) / N);
    out[2] = (float)(C / N);
  }
}

extern "C" void kernel_launch(void* const* d_in, const int* in_sizes, int n_in,
                              void* d_out, int out_size, void* d_ws,
                              size_t ws_size, hipStream_t stream) {
  const float* loc = (const float*)d_in[0];
  const float* conf = (const float*)d_in[1];
  const float* lm = (const float*)d_in[2];
  const float* priors = (const float*)d_in[3];
  const float* targets = (const float*)d_in[4];

  int P = in_sizes[3] / 4;
  int B = in_sizes[0] / (4 * P);
  int G = in_sizes[4] / (15 * B);
  int PTI = (P + 256 * PPI - 1) / (256 * PPI);
  int NIOU = B * PTI;
  int NGC = (G + GC - 1) / GC;
  int PC = 8;
  int NBP = B * NGC * PC;

  char* w = (char*)d_ws;
  size_t off = 0;
  // ---- zeroed region: bp only ----
  unsigned long long* bp = (unsigned long long*)(w + off);
  off += (size_t)B * G * 8;
  size_t clear_bytes = off;
  // ---- non-zeroed (written unconditionally every call) ----
  off = (off + 255) & ~(size_t)255;
  float* bto = (float*)(w + off);
  off += (size_t)B * P * 4;
  int* bti = (int*)(w + off);
  off += (size_t)B * P * 4;
  float* mine = (float*)(w + off);
  off += (size_t)B * P * 4;
  double* pll = (double*)(w + off);
  off += (size_t)NIOU * 8;
  double* pllm = (double*)(w + off);
  off += (size_t)NIOU * 8;
  double* plc = (double*)(w + off);
  off += (size_t)NIOU * 8;
  double* msum = (double*)(w + off);
  off += (size_t)NIOU * 8;
  int* pnp = (int*)(w + off);
  off += (size_t)NIOU * 4;
  off = (off + 7) & ~(size_t)7;
  double* dacc = (double*)(w + off);
  off += (size_t)B * 4 * 8;
  double* pllb = (double*)(w + off);
  off += (size_t)B * 8;
  double* pllmb = (double*)(w + off);
  off += (size_t)B * 8;
  double* plcb = (double*)(w + off);
  off += (size_t)B * 8;
  double* pfs_b = (double*)(w + off);
  off += (size_t)B * 8;
  int* dnpb = (int*)(w + off);
  off += (size_t)B * 4;
  int* anyv = (int*)(w + off);
  off += (size_t)B * 4;
  int* num_pos = (int*)(w + off);
  off += (size_t)B * 4;

  hipMemsetAsync(d_ws, 0, clear_bytes, stream);

  k_mm<<<NIOU + NBP, 256, 0, stream>>>(priors, targets, loc, conf, lm, bto,
                                       bti, bp, mine, pll, pllm, plc, msum,
                                       pnp, P, G, NIOU, PTI, NGC, PC);
  k_fix<<<B, G, 0, stream>>>(bp, bto, bti, conf, loc, lm, priors, targets,
                             mine, anyv, dacc, dnpb, P, G);
  k_tail<<<B, 1024, 0, stream>>>(pnp, msum, pll, pllm, plc, dacc, dnpb, anyv,
                                 mine, num_pos, pllb, pllmb, plcb, pfs_b, P,
                                 PTI);
  k_fin<<<1, 64, 0, stream>>>(pllb, pllmb, plcb, pfs_b, num_pos,
                              (float*)d_out, B);
}